// Round 1
// baseline (560.418 us; speedup 1.0000x reference)
//
#include <hip/hip_runtime.h>
#include <hip/hip_bf16.h>
#include <stdint.h>

// Problem dims (fixed for this problem instance)
#define MD 8192
#define ND 4096
#define KD 4096
#define RD 32

typedef __bf16 bf16x8 __attribute__((ext_vector_type(8)));
typedef float f32x4 __attribute__((ext_vector_type(4)));

// async 16B global->LDS (wave-uniform LDS base + lane*16 scatter)
__device__ __forceinline__ void cp16(const void* g, void* l) {
    __builtin_amdgcn_global_load_lds(
        (const __attribute__((address_space(1))) void*)g,
        (__attribute__((address_space(3))) void*)l, 16, 0, 0);
}

// ---------------------------------------------------------------------------
// Kernel 1: x fp32 -> bf16  (8 elems/thread, 16B stores)
// ---------------------------------------------------------------------------
__global__ __launch_bounds__(256) void cvt_x(const float* __restrict__ x,
                                             __hip_bfloat16* __restrict__ y) {
    size_t i = ((size_t)blockIdx.x * 256 + threadIdx.x) * 8;
    float4 a = *(const float4*)(x + i);
    float4 b = *(const float4*)(x + i + 4);
    union { __hip_bfloat16 h[8]; uint4 u; } o;
    o.h[0] = __float2bfloat16(a.x); o.h[1] = __float2bfloat16(a.y);
    o.h[2] = __float2bfloat16(a.z); o.h[3] = __float2bfloat16(a.w);
    o.h[4] = __float2bfloat16(b.x); o.h[5] = __float2bfloat16(b.y);
    o.h[6] = __float2bfloat16(b.z); o.h[7] = __float2bfloat16(b.w);
    *(uint4*)(y + i) = o.u;
}

// ---------------------------------------------------------------------------
// Kernel 2: W_eff[n][k] = dequant_int4(qw, wscales) + wtscale * (pu @ pd)
// tile: 64 n x 128 k per block, 256 threads, thread = 8n x 4k
// ---------------------------------------------------------------------------
__global__ __launch_bounds__(256) void build_weff(
    const int* __restrict__ qw,        // [N][K/2] two nibbles per int
    const float* __restrict__ wsc,     // [K/64][N]
    const float* __restrict__ pd,      // [R][K]
    const float* __restrict__ pu,      // [N][R]
    const float* __restrict__ wts_p,   // [1]
    __hip_bfloat16* __restrict__ weff) // [N][K]
{
    __shared__ float pd_s[RD][128];  // 16 KB  [r][k]
    __shared__ float pu_t[RD][64];   // 8 KB   [r][n] (transposed)
    const int t = threadIdx.x;
    const int kb = blockIdx.x * 128;
    const int nb = blockIdx.y * 64;

    // stage pd tile: 32x128 floats = 1024 float4, coalesced
    for (int f = t; f < (RD * 128) / 4; f += 256) {
        int r = f >> 5;
        int c = (f & 31) << 2;
        *(float4*)&pd_s[r][c] = *(const float4*)(pd + (size_t)r * KD + kb + c);
    }
    // stage pu tile transposed: 64x32 floats = 512 float4
    for (int f = t; f < (64 * RD) / 4; f += 256) {
        int nl = f >> 3;
        int r4 = (f & 7) << 2;
        float4 v = *(const float4*)(pu + (size_t)(nb + nl) * RD + r4);
        pu_t[r4 + 0][nl] = v.x; pu_t[r4 + 1][nl] = v.y;
        pu_t[r4 + 2][nl] = v.z; pu_t[r4 + 3][nl] = v.w;
    }
    __syncthreads();

    const float wts = wts_p[0];
    const int kc = (t & 31) << 2;   // local k base (4 cols)
    const int ng = (t >> 5) << 3;   // local n base (8 rows)

    float acc[8][4];
#pragma unroll
    for (int i = 0; i < 8; ++i)
#pragma unroll
        for (int j = 0; j < 4; ++j) acc[i][j] = 0.f;

    for (int r = 0; r < RD; ++r) {
        float4 pdv = *(const float4*)&pd_s[r][kc];
        float4 pua = *(const float4*)&pu_t[r][ng];
        float4 pub = *(const float4*)&pu_t[r][ng + 4];
        float pus[8] = {pua.x, pua.y, pua.z, pua.w, pub.x, pub.y, pub.z, pub.w};
#pragma unroll
        for (int i = 0; i < 8; ++i) {
            acc[i][0] += pus[i] * pdv.x;
            acc[i][1] += pus[i] * pdv.y;
            acc[i][2] += pus[i] * pdv.z;
            acc[i][3] += pus[i] * pdv.w;
        }
    }

    const int kg = kb + kc;       // global k base; 4 k's share one group
    const int g = kg >> 6;        // group index (GROUP_SIZE=64)
#pragma unroll
    for (int i = 0; i < 8; ++i) {
        const int n = nb + ng + i;
        const float sc = wsc[(size_t)g * ND + n];
        int2 q = *(const int2*)(qw + (size_t)n * (KD / 2) + (kg >> 1));
        const int w0 = (q.x & 15) - 8;
        const int w1 = ((q.x >> 4) & 15) - 8;
        const int w2 = (q.y & 15) - 8;
        const int w3 = ((q.y >> 4) & 15) - 8;
        union { __hip_bfloat16 h[4]; uint2 u; } o;
        o.h[0] = __float2bfloat16((float)w0 * sc + wts * acc[i][0]);
        o.h[1] = __float2bfloat16((float)w1 * sc + wts * acc[i][1]);
        o.h[2] = __float2bfloat16((float)w2 * sc + wts * acc[i][2]);
        o.h[3] = __float2bfloat16((float)w3 * sc + wts * acc[i][3]);
        *(uint2*)(weff + (size_t)n * KD + kg) = o.u;
    }
}

// ---------------------------------------------------------------------------
// Kernel 3: C[M][N] = A[M][K](bf16) * B[N][K](bf16)^T + bias   (m97 structure)
// 128x128 tile, BK=32, 256 threads = 4 waves (2x2), wave = 64x64 (4x4 MFMA)
// ---------------------------------------------------------------------------
__global__ __launch_bounds__(256) void gemm_bt_bias(
    const __hip_bfloat16* __restrict__ A,  // [M][K]
    const __hip_bfloat16* __restrict__ B,  // [N][K]
    const float* __restrict__ bias,        // [N]
    float* __restrict__ C)                 // [M][N]
{
    __shared__ alignas(16) __hip_bfloat16 As[128 * 32]; // 8 KB, row-major [m][k]
    __shared__ alignas(16) __hip_bfloat16 Bs[128 * 32]; // 8 KB, row-major [n][k]

    const int t = threadIdx.x;
    const int lane = t & 63;
    const int wave = t >> 6;
    const int wr = wave >> 1;   // wave row (m)  0..1
    const int wc = wave & 1;    // wave col (n)  0..1
    const int m0 = blockIdx.y * 128;
    const int n0 = blockIdx.x * 128;

    // staging map: pass p covers rows p*64..p*64+63; thread t -> row t/4, col (t%4)*8
    const int srow = t >> 2;
    const int scol = (t & 3) * 8;
    const __hip_bfloat16* Ag = A + (size_t)(m0 + srow) * KD + scol;
    const __hip_bfloat16* Bg = B + (size_t)(n0 + srow) * KD + scol;
    char* AsB = (char*)As + wave * 1024;  // wave-uniform LDS base, pass 0
    char* BsB = (char*)Bs + wave * 1024;

    const int qm = lane & 15;        // row-within-16 (A: m, B: n)
    const int ko = (lane >> 4) * 8;  // k offset 0/8/16/24

    f32x4 acc[4][4];
#pragma unroll
    for (int i = 0; i < 4; ++i)
#pragma unroll
        for (int j = 0; j < 4; ++j) acc[i][j] = (f32x4){0.f, 0.f, 0.f, 0.f};

    for (int kt = 0; kt < KD; kt += 32) {
        // stage A,B tiles: 2 passes each, 16B/lane async
        cp16(Ag + kt, AsB);
        cp16(Ag + kt + 64 * KD, AsB + 4096);
        cp16(Bg + kt, BsB);
        cp16(Bg + kt + 64 * KD, BsB + 4096);
        __syncthreads();

        bf16x8 af[4], bfr[4];
#pragma unroll
        for (int i = 0; i < 4; ++i)
            af[i] = *(const bf16x8*)(As + (wr * 64 + i * 16 + qm) * 32 + ko);
#pragma unroll
        for (int j = 0; j < 4; ++j)
            bfr[j] = *(const bf16x8*)(Bs + (wc * 64 + j * 16 + qm) * 32 + ko);

#pragma unroll
        for (int i = 0; i < 4; ++i)
#pragma unroll
            for (int j = 0; j < 4; ++j)
                acc[i][j] = __builtin_amdgcn_mfma_f32_16x16x32_bf16(
                    af[i], bfr[j], acc[i][j], 0, 0, 0);
        __syncthreads();
    }

    // epilogue: C/D layout col=lane&15, row=(lane>>4)*4+reg
    const int cm0 = (lane >> 4) * 4;
    const int cn = lane & 15;
#pragma unroll
    for (int j = 0; j < 4; ++j) {
        const int n = n0 + wc * 64 + j * 16 + cn;
        const float bv = bias[n];
#pragma unroll
        for (int i = 0; i < 4; ++i) {
            const int mr = m0 + wr * 64 + i * 16 + cm0;
            float* dst = C + (size_t)mr * ND + n;
#pragma unroll
            for (int r = 0; r < 4; ++r)
                dst[(size_t)r * ND] = acc[i][j][r] + bv;
        }
    }
}

// ---------------------------------------------------------------------------
extern "C" void kernel_launch(void* const* d_in, const int* in_sizes, int n_in,
                              void* d_out, int out_size, void* d_ws, size_t ws_size,
                              hipStream_t stream) {
    const float* x    = (const float*)d_in[0];   // [M][K] fp32
    const int* qw     = (const int*)d_in[1];     // [N][K/2]
    const float* wsc  = (const float*)d_in[2];   // [K/64][N]
    const float* pd   = (const float*)d_in[3];   // [R][K]
    const float* pu   = (const float*)d_in[4];   // [N][R]
    const float* wts  = (const float*)d_in[5];   // [1]
    const float* bias = (const float*)d_in[6];   // [N]
    float* out = (float*)d_out;                  // [M][N] fp32

    // workspace: W_eff bf16 (33.5 MB) then x bf16 (67 MB) = 100.7 MB
    __hip_bfloat16* weff = (__hip_bfloat16*)d_ws;
    __hip_bfloat16* xbf  = (__hip_bfloat16*)((char*)d_ws + (size_t)ND * KD * sizeof(__hip_bfloat16));

    cvt_x<<<(MD * (size_t)KD) / (256 * 8), 256, 0, stream>>>(x, xbf);
    build_weff<<<dim3(KD / 128, ND / 64), 256, 0, stream>>>(qw, wsc, pd, pu, wts, weff);
    gemm_bt_bias<<<dim3(ND / 128, MD / 128), 256, 0, stream>>>(xbf, weff, bias, out);
}